// Round 2
// baseline (323.681 us; speedup 1.0000x reference)
//
#include <hip/hip_runtime.h>
#include <hip/hip_bf16.h>

typedef unsigned short u16;
typedef unsigned int u32;
typedef __attribute__((ext_vector_type(8))) short short8;
typedef __attribute__((ext_vector_type(4))) float f32x4;

#define NN 8192
#define FIN 512
#define FOUT 128
#define NEG 0.2f

__device__ __forceinline__ u16 f2bf(float f) {
  u32 u = __builtin_bit_cast(u32, f);
  u32 r = (u + 0x7fffu + ((u >> 16) & 1u)) >> 16;
  return (u16)r;
}

// K1: h = x @ w  (fp32), also emit Hb = bf16(h) in blocked-transposed-swizzled
// layout: Hb[chunk c][col n][jj ^ ((n&7)<<3)] with c=row/128, jj=row%128.
__global__ __launch_bounds__(256) void k_h(const float* __restrict__ x,
                                           const float* __restrict__ w,
                                           float* __restrict__ h,
                                           u16* __restrict__ hb) {
  __shared__ float xs[32][68];
  __shared__ float ws_[64][128];
  const int t = threadIdx.x;
  const int r0 = blockIdx.x * 32;
  const int r = t >> 3;
  const int cq = (t & 7) * 4;
  float acc[4][4] = {};
  for (int kc = 0; kc < FIN; kc += 64) {
    __syncthreads();
    {
      const int rr = t >> 3, cc = (t & 7) * 8;
      const float4* src = (const float4*)(x + (size_t)(r0 + rr) * FIN + kc + cc);
      *(float4*)&xs[rr][cc] = src[0];
      *(float4*)&xs[rr][cc + 4] = src[1];
    }
#pragma unroll
    for (int i = 0; i < 8; ++i) {
      const int off = i * 1024 + t * 4;
      const int wr = off >> 7, wc = off & 127;
      *(float4*)&ws_[wr][wc] = *(const float4*)(w + (size_t)(kc + wr) * FOUT + wc);
    }
    __syncthreads();
    for (int kk = 0; kk < 64; ++kk) {
      const float xv = xs[r][kk];
#pragma unroll
      for (int g = 0; g < 4; ++g) {
        const float4 wv = *(const float4*)&ws_[kk][cq + 32 * g];
        acc[g][0] = fmaf(xv, wv.x, acc[g][0]);
        acc[g][1] = fmaf(xv, wv.y, acc[g][1]);
        acc[g][2] = fmaf(xv, wv.z, acc[g][2]);
        acc[g][3] = fmaf(xv, wv.w, acc[g][3]);
      }
    }
  }
  const int rg = r0 + r;
  const int ch = rg >> 7;
  const int jj = rg & 127;
#pragma unroll
  for (int g = 0; g < 4; ++g) {
    float4 v;
    v.x = acc[g][0]; v.y = acc[g][1]; v.z = acc[g][2]; v.w = acc[g][3];
    *(float4*)(h + (size_t)rg * FOUT + cq + 32 * g) = v;
#pragma unroll
    for (int e = 0; e < 4; ++e) {
      const int n = cq + 32 * g + e;
      hb[(size_t)ch * 16384 + n * 128 + (jj ^ ((n & 7) << 3))] = f2bf(acc[g][e]);
    }
  }
}

// K2: s = h @ a[:128], t = h @ a[128:].  One wave per row.
__global__ __launch_bounds__(256) void k_scores(const float* __restrict__ h,
                                                const float* __restrict__ a,
                                                float* __restrict__ s,
                                                float* __restrict__ t) {
  const int wid = threadIdx.x >> 6, lane = threadIdx.x & 63;
  const int row = blockIdx.x * 4 + wid;
  const float2 hv = *(const float2*)(h + (size_t)row * FOUT + lane * 2);
  const float2 a0 = *(const float2*)(a + lane * 2);
  const float2 a1 = *(const float2*)(a + FOUT + lane * 2);
  float ps = hv.x * a0.x + hv.y * a0.y;
  float pt = hv.x * a1.x + hv.y * a1.y;
#pragma unroll
  for (int d = 1; d < 64; d <<= 1) {
    ps += __shfl_xor(ps, d);
    pt += __shfl_xor(pt, d);
  }
  if (lane == 0) { s[row] = ps; t[row] = pt; }
}

// K3: tmax = max(t)
__global__ __launch_bounds__(256) void k_tmax(const float* __restrict__ t,
                                              float* __restrict__ tmax) {
  __shared__ float red[256];
  float m = -1e30f;
  for (int i = threadIdx.x; i < NN; i += 256) m = fmaxf(m, t[i]);
  red[threadIdx.x] = m;
  __syncthreads();
  for (int s2 = 128; s2 > 0; s2 >>= 1) {
    if (threadIdx.x < s2) red[threadIdx.x] = fmaxf(red[threadIdx.x], red[threadIdx.x + s2]);
    __syncthreads();
  }
  if (threadIdx.x == 0) tmax[0] = red[0];
}

// K4: 16 rows per block. Pass A: 8 waves x 2 rows stream adj once -> transposed
// bitmask in LDS + denominators (safe upper-bound max m_i = lrelu(s_i+tmax)).
// Pass B: BARRIER-FREE — waves split columns (1024 each); each lane computes p
// directly in MFMA A-fragment order (row=lane&15, k=kg*8+e), writes fp32 att,
// feeds bf16 MFMA. h' partials merged once via LDS atomicAdd at the end.
__global__ __launch_bounds__(512, 4) void k_attn(const int* __restrict__ adj,
                                                 const float* __restrict__ sg,
                                                 const float* __restrict__ tg,
                                                 const float* __restrict__ tmaxp,
                                                 const u16* __restrict__ hb,
                                                 float* __restrict__ att,
                                                 float* __restrict__ hp) {
  __shared__ u32 maskt[256 * 16];    // 16 KB: [word][row] transposed bitmask
  __shared__ float hsum[16 * 132];   // 8.25 KB padded h' accumulator
  __shared__ float s_s[16], s_m[16], s_l[16], s_inv[16];
  const int tid = threadIdx.x;
  const int w = tid >> 6, lane = tid & 63;
  const int r0 = blockIdx.x << 4;

  for (int i = tid; i < 16 * 132; i += 512) hsum[i] = 0.f;
  if (tid < 16) {
    const float sv = sg[r0 + tid];
    const float v = sv + tmaxp[0];
    s_s[tid] = sv;
    s_m[tid] = fmaxf(v, NEG * v);   // lrelu(s_i + tmax) >= all row entries
  }
  __syncthreads();

  // ---- Pass A: adj stream, denominators, bitmask ----
  const int rA = 2 * w, rB = rA + 1;
  const float sA = s_s[rA], mA = s_m[rA];
  const float sB = s_s[rB], mB = s_m[rB];
  float sum0 = 0.f, sum1 = 0.f;
  {
    const int4* adjA = (const int4*)(adj + (size_t)(r0 + rA) * NN);
    const int4* adjB = (const int4*)(adj + (size_t)(r0 + rB) * NN);
#pragma unroll 4
    for (int it = 0; it < 32; ++it) {
      const int jb = it * 256;
      const int4 a0 = adjA[it * 64 + lane];
      const int4 a1 = adjB[it * 64 + lane];
      const float4 tv = *(const float4*)(tg + jb + lane * 4);
      u32 nib0 = 0u, nib1 = 0u;
      {
        float e, p, sm = 0.f;
        e = sA + tv.x; e = fmaxf(e, NEG * e); p = __expf(e - mA); sm += (a0.x > 0) ? p : 0.f; nib0 |= (a0.x > 0) ? 1u : 0u;
        e = sA + tv.y; e = fmaxf(e, NEG * e); p = __expf(e - mA); sm += (a0.y > 0) ? p : 0.f; nib0 |= (a0.y > 0) ? 2u : 0u;
        e = sA + tv.z; e = fmaxf(e, NEG * e); p = __expf(e - mA); sm += (a0.z > 0) ? p : 0.f; nib0 |= (a0.z > 0) ? 4u : 0u;
        e = sA + tv.w; e = fmaxf(e, NEG * e); p = __expf(e - mA); sm += (a0.w > 0) ? p : 0.f; nib0 |= (a0.w > 0) ? 8u : 0u;
        sum0 += sm;
      }
      {
        float e, p, sm = 0.f;
        e = sB + tv.x; e = fmaxf(e, NEG * e); p = __expf(e - mB); sm += (a1.x > 0) ? p : 0.f; nib1 |= (a1.x > 0) ? 1u : 0u;
        e = sB + tv.y; e = fmaxf(e, NEG * e); p = __expf(e - mB); sm += (a1.y > 0) ? p : 0.f; nib1 |= (a1.y > 0) ? 2u : 0u;
        e = sB + tv.z; e = fmaxf(e, NEG * e); p = __expf(e - mB); sm += (a1.z > 0) ? p : 0.f; nib1 |= (a1.z > 0) ? 4u : 0u;
        e = sB + tv.w; e = fmaxf(e, NEG * e); p = __expf(e - mB); sm += (a1.w > 0) ? p : 0.f; nib1 |= (a1.w > 0) ? 8u : 0u;
        sum1 += sm;
      }
      u32 v0 = nib0;
      v0 |= __shfl_xor(v0, 1) << 4;
      v0 |= __shfl_xor(v0, 2) << 8;
      v0 |= __shfl_xor(v0, 4) << 16;
      u32 v1 = nib1;
      v1 |= __shfl_xor(v1, 1) << 4;
      v1 |= __shfl_xor(v1, 2) << 8;
      v1 |= __shfl_xor(v1, 4) << 16;
      if ((lane & 7) == 0) {
        const int wi = (jb >> 5) + (lane >> 3);
        maskt[wi * 16 + rA] = v0;
        maskt[wi * 16 + rB] = v1;
      }
    }
  }
#pragma unroll
  for (int d = 1; d < 64; d <<= 1) {
    sum0 += __shfl_xor(sum0, d);
    sum1 += __shfl_xor(sum1, d);
  }
  if (lane == 0) { s_l[rA] = sum0; s_l[rB] = sum1; }
  __syncthreads();
  if (tid < 16) s_inv[tid] = 1.0f / s_l[tid];
  __syncthreads();

  // ---- Pass B: barrier-free fragment-order p + att write + MFMA ----
  const int arow = lane & 15, kg = lane >> 4;
  const float sR = s_s[arow], mR = s_m[arow], invR = s_inv[arow];
  const int swz = (arow & 7) << 3;
  f32x4 acc[8];
#pragma unroll
  for (int i = 0; i < 8; ++i) acc[i] = (f32x4){0.f, 0.f, 0.f, 0.f};

  const int ck0 = w * 8;  // this wave's 8 chunks of 128 cols
  for (int ckl = 0; ckl < 8; ++ckl) {
    const int ckg = ck0 + ckl;
    const int j0 = ckg << 7;
    const u16* hc = hb + (size_t)ckg * 16384;
#pragma unroll
    for (int ks = 0; ks < 4; ++ks) {
      const u32 wd = maskt[(ckg * 4 + ks) * 16 + arow];
      const u32 byte_ = (wd >> (kg * 8)) & 0xffu;
      const int jc = j0 + ks * 32 + kg * 8;
      const float4 ta = *(const float4*)(tg + jc);
      const float4 tb = *(const float4*)(tg + jc + 4);
      const float tvv[8] = {ta.x, ta.y, ta.z, ta.w, tb.x, tb.y, tb.z, tb.w};
      float p[8];
#pragma unroll
      for (int e = 0; e < 8; ++e) {
        float ev = sR + tvv[e];
        ev = fmaxf(ev, NEG * ev);
        const float pe = __expf(ev - mR) * invR;
        p[e] = ((byte_ >> e) & 1u) ? pe : 0.f;
      }
      float* ap = att + (size_t)(r0 + arow) * NN + jc;
      float4 o0; o0.x = p[0]; o0.y = p[1]; o0.z = p[2]; o0.w = p[3];
      float4 o1; o1.x = p[4]; o1.y = p[5]; o1.z = p[6]; o1.w = p[7];
      *(float4*)ap = o0;
      *(float4*)(ap + 4) = o1;
      union { short8 s8; u32 u[4]; } afu;
#pragma unroll
      for (int h2 = 0; h2 < 4; ++h2)
        afu.u[h2] = (u32)f2bf(p[2 * h2]) | ((u32)f2bf(p[2 * h2 + 1]) << 16);
      const int ko = (ks * 32 + kg * 8) ^ swz;
#pragma unroll
      for (int nt = 0; nt < 8; ++nt) {
        const short8 bf = *(const short8*)(hc + (nt * 16 + arow) * 128 + ko);
        acc[nt] = __builtin_amdgcn_mfma_f32_16x16x32_bf16(afu.s8, bf, acc[nt], 0, 0, 0);
      }
    }
  }
  // merge partials (once per block)
#pragma unroll
  for (int nt = 0; nt < 8; ++nt)
#pragma unroll
    for (int q = 0; q < 4; ++q)
      atomicAdd(&hsum[(kg * 4 + q) * 132 + nt * 16 + arow], acc[nt][q]);
  __syncthreads();
  for (int i = tid; i < 2048; i += 512) {
    hp[(size_t)(r0 + (i >> 7)) * FOUT + (i & 127)] = hsum[(i >> 7) * 132 + (i & 127)];
  }
}

extern "C" void kernel_launch(void* const* d_in, const int* in_sizes, int n_in,
                              void* d_out, int out_size, void* d_ws, size_t ws_size,
                              hipStream_t stream) {
  const float* x = (const float*)d_in[0];
  const int* adj = (const int*)d_in[1];
  const float* w = (const float*)d_in[2];
  const float* a = (const float*)d_in[3];
  float* out = (float*)d_out;
  float* att = out;
  float* hp = out + (size_t)NN * NN;  // h' slot
  float* h = hp;                      // fp32 h scratch (consumed before K4 writes)
  u16* hb = (u16*)d_ws;               // 2 MB blocked-transposed bf16 h
  float* s = (float*)((char*)d_ws + (size_t)NN * FOUT * sizeof(u16));
  float* t = s + NN;
  float* tmax = t + NN;

  k_h<<<256, 256, 0, stream>>>(x, w, h, hb);
  k_scores<<<2048, 256, 0, stream>>>(h, a, s, t);
  k_tmax<<<1, 256, 0, stream>>>(t, tmax);
  k_attn<<<512, 512, 0, stream>>>(adj, s, t, tmax, hb, att, hp);
}